// Round 5
// baseline (94.140 us; speedup 1.0000x reference)
//
#include <hip/hip_runtime.h>
#include <hip/hip_fp16.h>

typedef __attribute__((ext_vector_type(8))) _Float16 half8;
typedef __attribute__((ext_vector_type(4))) float f32x4;

union U2H2 { unsigned int u; __half2 h; };

static __device__ __forceinline__ unsigned int pack2h(float a, float b) {
    U2H2 c; c.h = __floats2half2_rn(a, b); return c.u;
}
static __device__ __forceinline__ __half2 u_as_h2(unsigned int u) {
    U2H2 c; c.u = u; return c.h;
}

// Kernel A: Wrh in MFMA-fragment order: Wrh[k][ot][l][e] = half(W[o, c*25+k])
//   o = ot*16 + (l&15), c = (l>>4)*8 + e  -> a wave's B-fragment load is contiguous
__global__ void prep_w(const float* __restrict__ W, unsigned short* __restrict__ Wrh) {
    int i = blockIdx.x * 256 + threadIdx.x;  // 25*2048 = 51200
    if (i >= 25 * 2048) return;
    int k = i >> 11;
    int r = i & 2047;
    int ot = r >> 9;
    int l = (r >> 3) & 63;
    int e = i & 7;
    int o = ot * 16 + (l & 15);
    int c = (l >> 4) * 8 + e;
    __half h = __float2half(W[o * 800 + c * 25 + k]);
    Wrh[i] = *reinterpret_cast<unsigned short*>(&h);
}

// Kernel B: x (B,C,N) fp32 -> xth [N][2][32] fp16 (both b halves share a 128B line)
__global__ __launch_bounds__(256) void transpose_x(const float* __restrict__ x,
                                                   unsigned short* __restrict__ xth, int N) {
    __shared__ float t[2][32][65];
    int n0 = blockIdx.x * 64, tid = threadIdx.x;
#pragma unroll
    for (int i = 0; i < 16; ++i) {
        int e = tid + 256 * i;           // [2][32][64]
        int b = e >> 11, c = (e >> 6) & 31, nl = e & 63;
        int n = n0 + nl;
        t[b][c][nl] = (n < N) ? x[(size_t)(b * 32 + c) * N + n] : 0.f;
    }
    __syncthreads();
    int nl = tid >> 2, q = tid & 3, n = n0 + nl;
    if (n < N) {
#pragma unroll
        for (int b = 0; b < 2; ++b) {
            uint4 p;
            p.x = pack2h(t[b][q * 8 + 0][nl], t[b][q * 8 + 1][nl]);
            p.y = pack2h(t[b][q * 8 + 2][nl], t[b][q * 8 + 3][nl]);
            p.z = pack2h(t[b][q * 8 + 4][nl], t[b][q * 8 + 5][nl]);
            p.w = pack2h(t[b][q * 8 + 6][nl], t[b][q * 8 + 7][nl]);
            *reinterpret_cast<uint4*>(xth + ((size_t)n * 64 + b * 32 + q * 8)) = p;
        }
    }
}

// Kernel C: fused gather + einsum + MFMA GEMM + bias.
// Lane assignment makes the weighted-gather result the MFMA A-fragment directly:
//   lane l of wave wv owns A-row 16*wv + (l&15), c-slice (l>>4)*8..+8.
// B-fragments load straight from fragment-ordered Wrh (L1/L2-hot, no LDS).
// -> no LDS in the main loop, no barriers, independent-wave pipelining.
__global__ __launch_bounds__(256, 4) void fused_main(
    const unsigned short* __restrict__ xth,  // [N][2][32] fp16
    const unsigned short* __restrict__ Wrh,  // [25][4][64][8] fp16 (fragment order)
    const float* __restrict__ bias,          // [64]
    const int* __restrict__ nidx,            // [N][25][3]
    const float* __restrict__ nw,            // [N][25][3]
    float* __restrict__ out,                 // [2][64][N] fp32
    int N)
{
    __shared__ unsigned int idxw[25 * 96];   // j | (half(w)<<16), [k][nl][t]

    const int tid = threadIdx.x;
    const int n0 = blockIdx.x * 32;

    // ---- preload all 25 k-slices of (idx, half(w)) ----
#pragma unroll
    for (int it = 0; it < 10; ++it) {
        int e = tid + 256 * it;
        if (e < 2400) {
            int nl = e / 75;
            int rem = e - nl * 75;
            int n = n0 + nl;
            unsigned int u = 0;
            if (n < N) {
                int j = nidx[(size_t)n0 * 75 + e];
                __half hw = __float2half(nw[(size_t)n0 * 75 + e]);
                u = (unsigned int)j |
                    ((unsigned int)*reinterpret_cast<unsigned short*>(&hw) << 16);
            }
            int kk = rem / 3, t = rem - kk * 3;
            idxw[(kk * 32 + nl) * 3 + t] = u;
        }
    }
    __syncthreads();

    const int wv = tid >> 6, l = tid & 63;
    const int c16 = l & 15, g = l >> 4;
    const int row = 16 * wv + c16;     // 0..63 = b*32 + nl  (this lane's A-row)
    const int b0 = row >> 5, nl0 = row & 31;
    const int xoff = b0 * 32 + g * 8;  // halfword offset within a 128B xth row

    uint4 rgA[3], rgB[3], rBA[4], rBB[4];
    unsigned int ruA[3], ruB[3];

    auto issue_g = [&](int kk, uint4 (&rg)[3], unsigned int (&ru)[3]) {
        const unsigned int* ip = &idxw[(kk * 32 + nl0) * 3];
#pragma unroll
        for (int t = 0; t < 3; ++t) {
            unsigned int u = ip[t];
            ru[t] = u;
            rg[t] = *reinterpret_cast<const uint4*>(
                xth + (int)(u & 0xffffu) * 64 + xoff);
        }
    };
    auto issue_B = [&](int kk, uint4 (&rB)[4]) {
        const unsigned short* bp = Wrh + kk * 2048 + l * 8;
#pragma unroll
        for (int ot = 0; ot < 4; ++ot)
            rB[ot] = *reinterpret_cast<const uint4*>(bp + ot * 512);
    };

    f32x4 acc[4];
#pragma unroll
    for (int ot = 0; ot < 4; ++ot) acc[ot] = (f32x4){0.f, 0.f, 0.f, 0.f};

    // prologue: depth-2 prefetch, oldest first
    issue_g(0, rgA, ruA); issue_B(0, rBA);
    issue_g(1, rgB, ruB); issue_B(1, rBB);

    auto body = [&](int kNext, uint4 (&rg)[3], unsigned int (&ru)[3], uint4 (&rB)[4]) {
        // A-fragment: weighted fp16 sum of the 3 gathered slices (in-register)
        __half2 w0 = u_as_h2(__builtin_amdgcn_perm(ru[0], ru[0], 0x03020302u));
        __half2 w1 = u_as_h2(__builtin_amdgcn_perm(ru[1], ru[1], 0x03020302u));
        __half2 w2 = u_as_h2(__builtin_amdgcn_perm(ru[2], ru[2], 0x03020302u));
        uint4 v0 = rg[0], v1 = rg[1], v2 = rg[2];
        uint4 p; U2H2 c;
        c.h = __hfma2(u_as_h2(v0.x), w0, __hfma2(u_as_h2(v1.x), w1, __hmul2(u_as_h2(v2.x), w2)));
        p.x = c.u;
        c.h = __hfma2(u_as_h2(v0.y), w0, __hfma2(u_as_h2(v1.y), w1, __hmul2(u_as_h2(v2.y), w2)));
        p.y = c.u;
        c.h = __hfma2(u_as_h2(v0.z), w0, __hfma2(u_as_h2(v1.z), w1, __hmul2(u_as_h2(v2.z), w2)));
        p.z = c.u;
        c.h = __hfma2(u_as_h2(v0.w), w0, __hfma2(u_as_h2(v1.w), w1, __hmul2(u_as_h2(v2.w), w2)));
        p.w = c.u;
        half8 af = __builtin_bit_cast(half8, p);

        issue_g(kNext, rg, ru);   // refill gathers (2 slices ahead) before MFMA

        __builtin_amdgcn_s_setprio(1);
#pragma unroll
        for (int ot = 0; ot < 4; ++ot) {
            half8 bf = __builtin_bit_cast(half8, rB[ot]);
            acc[ot] = __builtin_amdgcn_mfma_f32_16x16x32_f16(af, bf, acc[ot], 0, 0, 0);
        }
        __builtin_amdgcn_s_setprio(0);

        issue_B(kNext, rB);       // refill B after its last use
    };

    for (int kp = 0; kp < 12; ++kp) {
        int kE = 2 * kp + 2;                     // next even slice (<= 24)
        int kO = (2 * kp + 3 <= 24) ? 2 * kp + 3 : 24;
        body(kE, rgA, ruA, rBA);                 // slice 2*kp
        body(kO, rgB, ruB, rBB);                 // slice 2*kp+1
    }
    body(24, rgA, ruA, rBA);                     // slice 24 (refill harmless)

    // ---- epilogue: bias + store (D: col=lane&15 -> o, row=4*(lane>>4)+i -> m) ----
#pragma unroll
    for (int ot = 0; ot < 4; ++ot) {
        int o = ot * 16 + c16;
        float bv = bias[o];
#pragma unroll
        for (int i = 0; i < 4; ++i) {
            int mrow = 16 * wv + 4 * g + i;
            int b = mrow >> 5, nl = mrow & 31;
            int n = n0 + nl;
            if (n < N) out[(size_t)(b * 64 + o) * N + n] = acc[ot][i] + bv;
        }
    }
}

extern "C" void kernel_launch(void* const* d_in, const int* in_sizes, int n_in,
                              void* d_out, int out_size, void* d_ws, size_t ws_size,
                              hipStream_t stream) {
    const float* x    = (const float*)d_in[0];   // (2,32,N)
    const float* nw   = (const float*)d_in[1];   // (N,25,3)
    const float* W    = (const float*)d_in[2];   // (64,800)
    const float* bias = (const float*)d_in[3];   // (64,)
    const int*   nidx = (const int*)d_in[4];     // (N,25,3)
    float* out = (float*)d_out;

    int N = in_sizes[0] / 64;  // B*C = 64

    unsigned short* xth = (unsigned short*)d_ws;      // [N][2][32] fp16
    unsigned short* Wrh = xth + (size_t)N * 64;       // [25][4][64][8] fp16

    prep_w<<<(25 * 2048 + 255) / 256, 256, 0, stream>>>(W, Wrh);

    transpose_x<<<(N + 63) / 64, 256, 0, stream>>>(x, xth, N);

    fused_main<<<(N + 31) / 32, 256, 0, stream>>>(xth, Wrh, bias, nidx, nw, out, N);
}

// Round 6
// 63.056 us; speedup vs baseline: 1.4930x; 1.4930x over previous
//
#include <hip/hip_runtime.h>
#include <hip/hip_fp16.h>

typedef __attribute__((ext_vector_type(8))) _Float16 half8;
typedef __attribute__((ext_vector_type(4))) float f32x4;

union U2H2 { unsigned int u; __half2 h; };

static __device__ __forceinline__ unsigned int pack2h(float a, float b) {
    U2H2 c; c.h = __floats2half2_rn(a, b); return c.u;
}
static __device__ __forceinline__ __half2 u_as_h2(unsigned int u) {
    U2H2 c; c.u = u; return c.h;
}

// swizzle: slot' = slot ^ s(row), s(row) = (row&3)^((row>>2)&3)  (verified conflict-free
// for both the 4-lane-per-row write pattern and the 16-row MFMA read pattern)
#define SWZ(row, slot) ((slot) ^ ((row) & 3) ^ (((row) >> 2) & 3))

// fence LDS + barrier WITHOUT draining vmcnt (keeps prefetched gathers in flight)
#define LDS_BARRIER()                                                \
    do {                                                             \
        asm volatile("s_waitcnt lgkmcnt(0)" ::: "memory");           \
        __builtin_amdgcn_s_barrier();                                \
        __builtin_amdgcn_sched_barrier(0);                           \
    } while (0)

// Kernel B+A fused: blocks [0, nT) transpose x -> xth [N][2][32] fp16;
// blocks [nT, nT+25) repack W -> Wrh[k][o][c] fp16.
__global__ __launch_bounds__(256) void prep_all(const float* __restrict__ x,
                                                const float* __restrict__ W,
                                                unsigned short* __restrict__ xth,
                                                unsigned short* __restrict__ Wrh,
                                                int N, int nT) {
    int bid = blockIdx.x, tid = threadIdx.x;
    if (bid >= nT) {
        int k = bid - nT;  // 0..24
#pragma unroll
        for (int it = 0; it < 8; ++it) {
            int r = tid + 256 * it;           // 0..2047 = o*32+c
            int o = r >> 5, c = r & 31;
            __half h = __float2half(W[o * 800 + c * 25 + k]);
            Wrh[k * 2048 + r] = *reinterpret_cast<unsigned short*>(&h);
        }
        return;
    }
    __shared__ float t[2][32][65];
    int n0 = bid * 64;
#pragma unroll
    for (int i = 0; i < 16; ++i) {
        int e = tid + 256 * i;               // [2][32][64]
        int b = e >> 11, c = (e >> 6) & 31, nl = e & 63;
        int n = n0 + nl;
        t[b][c][nl] = (n < N) ? x[(size_t)(b * 32 + c) * N + n] : 0.f;
    }
    __syncthreads();
    int nl = tid >> 2, q = tid & 3, n = n0 + nl;
    if (n < N) {
#pragma unroll
        for (int b = 0; b < 2; ++b) {
            uint4 p;
            p.x = pack2h(t[b][q * 8 + 0][nl], t[b][q * 8 + 1][nl]);
            p.y = pack2h(t[b][q * 8 + 2][nl], t[b][q * 8 + 3][nl]);
            p.z = pack2h(t[b][q * 8 + 4][nl], t[b][q * 8 + 5][nl]);
            p.w = pack2h(t[b][q * 8 + 6][nl], t[b][q * 8 + 7][nl]);
            *reinterpret_cast<uint4*>(xth + ((size_t)n * 64 + b * 32 + q * 8)) = p;
        }
    }
}

// Kernel C: fused gather + einsum + MFMA GEMM + bias (depth-4 gather pipeline)
__global__ __launch_bounds__(256) void fused_main(
    const unsigned short* __restrict__ xth,  // [N][2][32] fp16
    const unsigned short* __restrict__ Wrh,  // [25][64][32] fp16
    const float* __restrict__ bias,          // [64]
    const int* __restrict__ nidx,            // [N][25][3]
    const float* __restrict__ nw,            // [N][25][3]
    float* __restrict__ out,                 // [2][64][N] fp32
    int N)
{
    __shared__ unsigned int idxw[32 * 75];                  // [nl][k*3+t]: j | half(w)<<16
    __shared__ __align__(16) unsigned char sA[2][4096];     // double-buffered A slice
    __shared__ __align__(16) unsigned char sB[2][4096];     // double-buffered B slice

    const int tid = threadIdx.x;
    const int n0 = blockIdx.x * 32;

    // ---- preload (idx, half(w)) for all 25 slices: direct copy, layout [nl][75] ----
#pragma unroll
    for (int it = 0; it < 10; ++it) {
        int e = tid + 256 * it;
        if (e < 2400) {
            int n = n0 + e / 75;
            unsigned int u = 0;
            if (n < N) {
                int j = nidx[(size_t)n0 * 75 + e];
                __half hw = __float2half(nw[(size_t)n0 * 75 + e]);
                u = (unsigned int)j |
                    ((unsigned int)*reinterpret_cast<unsigned short*>(&hw) << 16);
            }
            idxw[e] = u;
        }
    }
    __syncthreads();

    const int row = tid >> 2;      // 0..63 = b*32+nl (gather row this thread owns)
    const int l4  = tid & 3;       // 16B slice within 64B
    const int b0  = row >> 5;
    const int nl0 = row & 31;

    const int wr_off = row * 64 + (SWZ(row, l4) << 4);   // sA / sB write offset

    const int l = tid & 63, wv = tid >> 6, c16 = l & 15, g = l >> 4;
    const int arow = 16 * wv + c16;
    const int rd_a = arow * 64 + (SWZ(arow, g) << 4);

    uint4 rg0[3], rg1[3], rg2[3], rg3[3];
    unsigned int ru0[3], ru1[3], ru2[3], ru3[3];
    uint4 rB;

    const unsigned int* iprow = &idxw[nl0 * 75];

#define ISSUE_G(kk, RG, RU)                                                     \
    do {                                                                        \
        _Pragma("unroll")                                                       \
        for (int t = 0; t < 3; ++t) {                                           \
            unsigned int u = iprow[(kk) * 3 + t];                               \
            RU[t] = u;                                                          \
            RG[t] = *reinterpret_cast<const uint4*>(                            \
                xth + (int)(u & 0xffffu) * 64 + b0 * 32 + l4 * 8);              \
        }                                                                       \
    } while (0)

    f32x4 acc[4];
#pragma unroll
    for (int ot = 0; ot < 4; ++ot) acc[ot] = (f32x4){0.f, 0.f, 0.f, 0.f};

    // prologue: B(0) first (needed first), then gathers 0..3 oldest-first
    rB = *reinterpret_cast<const uint4*>(Wrh + tid * 8);
    ISSUE_G(0, rg0, ru0);
    ISSUE_G(1, rg1, ru1);
    ISSUE_G(2, rg2, ru2);
    ISSUE_G(3, rg3, ru3);

#define BODY(K, BUF, RG, RU)                                                       \
    do {                                                                           \
        const int k_ = (K);                                                        \
        /* consume rB -> sB; refill B(k+1) */                                      \
        *reinterpret_cast<uint4*>(&sB[BUF][wr_off]) = rB;                          \
        if (k_ + 1 < 25)                                                           \
            rB = *reinterpret_cast<const uint4*>(Wrh + (k_ + 1) * 2048 + tid * 8); \
        /* consume gathers -> weighted fp16 sum -> sA */                           \
        {                                                                          \
            __half2 w0 = u_as_h2(__builtin_amdgcn_perm(RU[0], RU[0], 0x03020302u));\
            __half2 w1 = u_as_h2(__builtin_amdgcn_perm(RU[1], RU[1], 0x03020302u));\
            __half2 w2 = u_as_h2(__builtin_amdgcn_perm(RU[2], RU[2], 0x03020302u));\
            uint4 v0 = RG[0], v1 = RG[1], v2 = RG[2];                              \
            uint4 p; U2H2 c;                                                       \
            c.h = __hfma2(u_as_h2(v0.x), w0,                                       \
                  __hfma2(u_as_h2(v1.x), w1, __hmul2(u_as_h2(v2.x), w2)));         \
            p.x = c.u;                                                             \
            c.h = __hfma2(u_as_h2(v0.y), w0,                                       \
                  __hfma2(u_as_h2(v1.y), w1, __hmul2(u_as_h2(v2.y), w2)));         \
            p.y = c.u;                                                             \
            c.h = __hfma2(u_as_h2(v0.z), w0,                                       \
                  __hfma2(u_as_h2(v1.z), w1, __hmul2(u_as_h2(v2.z), w2)));         \
            p.z = c.u;                                                             \
            c.h = __hfma2(u_as_h2(v0.w), w0,                                       \
                  __hfma2(u_as_h2(v1.w), w1, __hmul2(u_as_h2(v2.w), w2)));         \
            p.w = c.u;                                                             \
            *reinterpret_cast<uint4*>(&sA[BUF][wr_off]) = p;                       \
        }                                                                          \
        /* refill this gather buffer 4 slices ahead */                             \
        if (k_ + 4 < 25) ISSUE_G(k_ + 4, RG, RU);                                  \
        /* one barrier: LDS visible, vmem prefetch stays in flight */              \
        LDS_BARRIER();                                                             \
        /* MFMA from LDS */                                                        \
        {                                                                          \
            half8 af = *reinterpret_cast<const half8*>(&sA[BUF][rd_a]);            \
            _Pragma("unroll")                                                      \
            for (int ot = 0; ot < 4; ++ot) {                                       \
                int orow = ot * 16 + c16;                                          \
                half8 bf = *reinterpret_cast<const half8*>(                        \
                    &sB[BUF][orow * 64 + (SWZ(orow, g) << 4)]);                    \
                acc[ot] =                                                          \
                    __builtin_amdgcn_mfma_f32_16x16x32_f16(af, bf, acc[ot], 0, 0, 0);\
            }                                                                      \
        }                                                                          \
    } while (0)

    for (int kp = 0; kp < 6; ++kp) {
        int k0 = kp * 4;
        BODY(k0 + 0, 0, rg0, ru0);
        BODY(k0 + 1, 1, rg1, ru1);
        BODY(k0 + 2, 0, rg2, ru2);
        BODY(k0 + 3, 1, rg3, ru3);
    }
    BODY(24, 0, rg0, ru0);

    // ---- epilogue: bias + store (D: col=lane&15 -> o, row=4*(lane>>4)+i -> m) ----
#pragma unroll
    for (int ot = 0; ot < 4; ++ot) {
        int o = ot * 16 + c16;
        float bv = bias[o];
#pragma unroll
        for (int i = 0; i < 4; ++i) {
            int mrow = 16 * wv + 4 * g + i;
            int b = mrow >> 5, nl = mrow & 31;
            int n = n0 + nl;
            if (n < N) out[(size_t)(b * 64 + o) * N + n] = acc[ot][i] + bv;
        }
    }
#undef BODY
#undef ISSUE_G
}

extern "C" void kernel_launch(void* const* d_in, const int* in_sizes, int n_in,
                              void* d_out, int out_size, void* d_ws, size_t ws_size,
                              hipStream_t stream) {
    const float* x    = (const float*)d_in[0];   // (2,32,N)
    const float* nw   = (const float*)d_in[1];   // (N,25,3)
    const float* W    = (const float*)d_in[2];   // (64,800)
    const float* bias = (const float*)d_in[3];   // (64,)
    const int*   nidx = (const int*)d_in[4];     // (N,25,3)
    float* out = (float*)d_out;

    int N = in_sizes[0] / 64;  // B*C = 64

    unsigned short* xth = (unsigned short*)d_ws;      // [N][2][32] fp16
    unsigned short* Wrh = xth + (size_t)N * 64;       // [25][64][32] fp16

    int nT = (N + 63) / 64;
    prep_all<<<nT + 25, 256, 0, stream>>>(x, W, xth, Wrh, N, nT);

    fused_main<<<(N + 31) / 32, 256, 0, stream>>>(xth, Wrh, bias, nidx, nw, out, N);
}